// Round 9
// baseline (377.547 us; speedup 1.0000x reference)
//
#include <hip/hip_runtime.h>

#define NQ 14
#define NL 6
#define DIM (1 << NQ)   // 16384 amplitudes
#define TPB 512

// ---------------------------------------------------------------------------
// One block (512 thr = 8 waves) per sample; state in 128 KiB static LDS
// (XOR-swizzled). Empirical allocator model (rounds 1-8): VGPR budget =
// 512KB/(2*TPB*256B) -- it ALWAYS assumes 2 workgroups/CU regardless of LDS
// or occupancy attributes. TPB=512 => budget 128. This kernel keeps live
// state at r[16] (32 VGPRs) in passes S0-S2 (two disjoint in-place halves)
// and r[32] only in the single S3 pass (read-all/barrier/permuted-write),
// peak live ~90 < 128 => structurally spill-free.
//
// Layer 0 is a product state: computed in registers, written through the
// layer-0 entangler permutation. Layers 1..5: 4 passes (4+4+4+2 gate wires);
// each layer's CNOT entangler is a GF(2)-linear index permutation folded
// into S3's writeback via compile-time tables (math verified, absmax 0.0).
// All LDS addresses are base_S(t) ^ delta_S(m) (swizzle is XOR-linear);
// in-place read/write patterns are bank-conflict-free (4 lanes/bank = b64
// minimum).
// ---------------------------------------------------------------------------
struct Tbl {
    unsigned short Wt[NL][TPB];
    unsigned short Wk[NL][32];
};

constexpr Tbl buildTbl() {
    Tbl T{};
    for (int l = 0; l < NL; ++l) {
        const int rng = l + 1;   // entangler range r = (l % (NQ-1)) + 1
        unsigned short col[NQ] = {};
        for (int p = 0; p < NQ; ++p) col[p] = (unsigned short)(1 << p);
        for (int w = 0; w < NQ; ++w) {
            int c = NQ - 1 - w;
            int g = NQ - 1 - ((w + rng) % NQ);
            col[c] ^= col[g];
        }
        unsigned int M[NQ] = {}, Inv[NQ] = {};
        for (int q = 0; q < NQ; ++q) {
            M[q] = 0;
            for (int p = 0; p < NQ; ++p) M[q] |= (unsigned)((col[p] >> q) & 1) << p;
            Inv[q] = 1u << q;
        }
        for (int cp = 0; cp < NQ; ++cp) {
            int piv = cp;
            while (!((M[piv] >> cp) & 1)) ++piv;
            unsigned tmp = M[piv]; M[piv] = M[cp]; M[cp] = tmp;
            tmp = Inv[piv]; Inv[piv] = Inv[cp]; Inv[cp] = tmp;
            for (int q = 0; q < NQ; ++q)
                if (q != cp && ((M[q] >> cp) & 1)) { M[q] ^= M[cp]; Inv[q] ^= Inv[cp]; }
        }
        unsigned short colInv[NQ] = {};
        for (int p = 0; p < NQ; ++p) {
            unsigned short v = 0;
            for (int q = 0; q < NQ; ++q) v |= (unsigned short)(((Inv[q] >> p) & 1) << q);
            colInv[p] = v;
        }
        // S3 coset shape (TPB=512, 32 amps/thread):
        //   t bits 0..8 -> h bits 3..11; m bits 2..4 -> h bits 0..2;
        //   m bits 0,1 -> h bits 12,13 (gated wires 1,0)
        for (int t = 0; t < TPB; ++t) {
            int ht = t << 3;
            int r2 = 0;
            for (int p = 0; p < NQ; ++p) if ((ht >> p) & 1) r2 ^= colInv[p];
            T.Wt[l][t] = (unsigned short)(r2 ^ ((r2 >> 6) & 63));
        }
        for (int m = 0; m < 32; ++m) {
            int hk = (m >> 2) | ((m & 3) << 12);
            int r2 = 0;
            for (int p = 0; p < NQ; ++p) if ((hk >> p) & 1) r2 ^= colInv[p];
            T.Wk[l][m] = (unsigned short)(r2 ^ ((r2 >> 6) & 63));
        }
    }
    return T;
}

__device__ const Tbl dT = buildTbl();

__device__ __forceinline__ int swz(int h) { return h ^ ((h >> 6) & 63); }

__device__ __forceinline__ float2 cmul(float2 a, float2 b) {
    return make_float2(a.x * b.x - a.y * b.y, a.x * b.y + a.y * b.x);
}

// logical h = t-part | m-part (disjoint bit fields); swz is XOR-linear, so
// physical addr = hbase<S>(t) ^ hdelta<S>(m), hdelta compile-time per m.
template <int S>
__device__ __forceinline__ int hbase(int t) {
    int h;
    if constexpr (S == 0)      h = t << 5;                        // t -> h 5..13
    else if constexpr (S == 1) h = (t & 15) | ((t >> 4) << 9);    // t -> h 0..3,9..13
    else if constexpr (S == 2) h = (t & 255) | ((t >> 8) << 13);  // t -> h 0..7,13
    else                       h = t << 3;                        // t -> h 3..11
    return swz(h);
}
template <int S>
constexpr int hdelta(int m) {
    int h;
    if (S == 0)      h = m;                         // m: k 0..3 -> h 0..3, half -> h 4
    else if (S == 1) h = m << 4;                    // k -> h 4..7, half -> h 8
    else if (S == 2) h = m << 8;                    // k -> h 8..11, half -> h 12
    else             h = (m >> 2) | ((m & 3) << 12);// m 0,1 -> h 12,13; m 2..4 -> h 0..2
    return h ^ ((h >> 6) & 63);
}

__device__ __forceinline__ void gate2(float2 u0, float2 u1, float2 u2, float2 u3,
                                      float2& A, float2& C) {
    float2 a = A, c = C, na, nc;
    na.x = u0.x * a.x - u0.y * a.y + u1.x * c.x - u1.y * c.y;
    na.y = u0.x * a.y + u0.y * a.x + u1.x * c.y + u1.y * c.x;
    nc.x = u2.x * a.x - u2.y * a.y + u3.x * c.x - u3.y * c.y;
    nc.y = u2.x * a.y + u2.y * a.x + u3.x * c.y + u3.y * c.x;
    A = na; C = nc;
}

// S0/S1/S2: 4 gates on k bits 0..3, two disjoint 16-amp halves (r[16] live).
template <int S>
__device__ __forceinline__ void doPassRMW(float2* st, const float2 (*U)[4], int l, int t) {
    const int base = hbase<S>(t);
#pragma unroll
    for (int half = 0; half < 2; ++half) {
        float2 r[16];
#pragma unroll
        for (int k = 0; k < 16; ++k) r[k] = st[base ^ hdelta<S>((half << 4) | k)];
#pragma unroll
        for (int j = 0; j < 4; ++j) {
            const int w = (S == 0) ? (13 - j) : (S == 1) ? (9 - j) : (5 - j);
            const float2* u = U[l * NQ + w];
            float2 u0 = u[0], u1 = u[1], u2 = u[2], u3 = u[3];
#pragma unroll
            for (int p = 0; p < 8; ++p) {
                const int k0 = ((p >> j) << (j + 1)) | (p & ((1 << j) - 1));
                gate2(u0, u1, u2, u3, r[k0], r[k0 | (1 << j)]);
            }
        }
#pragma unroll
        for (int k = 0; k < 16; ++k) st[base ^ hdelta<S>((half << 4) | k)] = r[k];
    }
}

// S3: 2 gates on m bits 0,1 (wires 1,0) + entangler-permuted writeback.
__device__ __forceinline__ void doPassPerm(float2* st, const float2 (*U)[4], int l, int t,
                                           const unsigned short* wt, const unsigned short* wk) {
    const int base = hbase<3>(t);
    float2 r[32];
#pragma unroll
    for (int m = 0; m < 32; ++m) r[m] = st[base ^ hdelta<3>(m)];
    __syncthreads();   // all reads done before permuted writes
#pragma unroll
    for (int j = 0; j < 2; ++j) {
        const float2* u = U[l * NQ + (1 - j)];
        float2 u0 = u[0], u1 = u[1], u2 = u[2], u3 = u[3];
#pragma unroll
        for (int p = 0; p < 16; ++p) {
            const int k0 = ((p >> j) << (j + 1)) | (p & ((1 << j) - 1));
            gate2(u0, u1, u2, u3, r[k0], r[k0 | (1 << j)]);
        }
    }
    const int at = wt[t];
#pragma unroll
    for (int m = 0; m < 32; ++m) st[at ^ wk[m]] = r[m];
}

__global__ __launch_bounds__(TPB)
void qc_kernel(const float* __restrict__ x,
               const float* __restrict__ wts,
               const float* __restrict__ fcw,
               const float* __restrict__ fcb,
               float* __restrict__ out)
{
    __shared__ float2 st[DIM];               // 128 KiB static LDS (swizzled layout)
    __shared__ float2 U[NL * NQ][4];         // Rot (layer0: Rot*RX) matrices
    __shared__ float2 R[NQ][4];              // RX matrices (temp)
    __shared__ float wsum[TPB / 64];

    const int b = blockIdx.x;
    const int t = threadIdx.x;

    // gate matrices
    if (t < NQ) {
        float th = 0.5f * x[b * NQ + t];
        float c = cosf(th), s = sinf(th);
        R[t][0] = make_float2(c, 0.f);
        R[t][1] = make_float2(0.f, -s);
        R[t][2] = make_float2(0.f, -s);
        R[t][3] = make_float2(c, 0.f);
    }
    if (t >= 64 && t < 64 + NL * NQ) {
        int g = t - 64;
        float phi = wts[g * 3 + 0];
        float th  = wts[g * 3 + 1];
        float om  = wts[g * 3 + 2];
        float c = cosf(0.5f * th), s = sinf(0.5f * th);
        float aa = 0.5f * (phi + om), dd = 0.5f * (phi - om);
        float ca = cosf(aa), sa = sinf(aa);
        float cd = cosf(dd), sd = sinf(dd);
        U[g][0] = make_float2( ca * c, -sa * c);
        U[g][1] = make_float2(-cd * s, -sd * s);
        U[g][2] = make_float2( cd * s, -sd * s);
        U[g][3] = make_float2( ca * c,  sa * c);
    }
    __syncthreads();

    // fold RX into layer-0 Rot: U0 = Rot * RX
    if (t < NQ) {
        float2 a00 = U[t][0], a01 = U[t][1], a10 = U[t][2], a11 = U[t][3];
        float2 b00 = R[t][0], b01 = R[t][1], b10 = R[t][2], b11 = R[t][3];
        auto ca2 = [](float2 p, float2 q) { return make_float2(p.x + q.x, p.y + q.y); };
        U[t][0] = ca2(cmul(a00, b00), cmul(a01, b10));
        U[t][1] = ca2(cmul(a00, b01), cmul(a01, b11));
        U[t][2] = ca2(cmul(a10, b00), cmul(a11, b10));
        U[t][3] = ca2(cmul(a10, b01), cmul(a11, b11));
    }
    __syncthreads();

    // ---- layer 0: product state (Rot*RX)|0> written through entangler-0 ----
    // S3 shape: h bit 3+i = t bit i (wire 10-i); m0->h12 (w1), m1->h13 (w0),
    // m2->h0 (w13), m3->h1 (w12), m4->h2 (w11). amp = prod cv[w][bit].
    {
        float2 A = make_float2(1.f, 0.f);
#pragma unroll
        for (int i = 0; i < 9; ++i)
            A = cmul(A, ((t >> i) & 1) ? U[10 - i][2] : U[10 - i][0]);
        const int at = dT.Wt[0][t];
        float2 q1[4];
#pragma unroll
        for (int ml = 0; ml < 4; ++ml)
            q1[ml] = cmul((ml & 1) ? U[1][2] : U[1][0],
                          (ml & 2) ? U[0][2] : U[0][0]);
#pragma unroll
        for (int mh = 0; mh < 8; ++mh) {
            float2 B = cmul(A, cmul(cmul((mh & 1) ? U[13][2] : U[13][0],
                                         (mh & 2) ? U[12][2] : U[12][0]),
                                    (mh & 4) ? U[11][2] : U[11][0]));
#pragma unroll
            for (int ml = 0; ml < 4; ++ml)
                st[at ^ dT.Wk[0][(mh << 2) | ml]] = cmul(B, q1[ml]);
        }
    }
    __syncthreads();

    // ---- layers 1..5: S0..S2 in-place halves, S3 + folded entangler ----
    for (int l = 1; l < NL; ++l) {
        doPassRMW<0>(st, U, l, t);
        __syncthreads();
        doPassRMW<1>(st, U, l, t);
        __syncthreads();
        doPassRMW<2>(st, U, l, t);
        __syncthreads();
        doPassPerm(st, U, l, t, dT.Wt[l], dT.Wk[l]);
        __syncthreads();
    }

    // ---- fused expectation + FC (storage identity-mapped, swizzled) ----
    // S0 shape: k bit j -> wire 13-j; half -> wire 9; t bit i -> wire 8-i.
    float fw[NQ];
#pragma unroll
    for (int w = 0; w < NQ; ++w) fw[w] = fcw[w];

    float gl = 0.f;
#pragma unroll
    for (int i = 0; i < 9; ++i) gl += ((t >> i) & 1) ? -fw[8 - i] : fw[8 - i];

    const int eb = hbase<0>(t);
    float acc = 0.f;
#pragma unroll
    for (int half = 0; half < 2; ++half) {
        float gh = gl + (half ? -fw[9] : fw[9]);
#pragma unroll
        for (int k = 0; k < 16; ++k) {
            float2 a = st[eb ^ hdelta<0>((half << 4) | k)];
            float p = a.x * a.x + a.y * a.y;
            float g = gh;
#pragma unroll
            for (int j = 0; j < 4; ++j)
                g += ((k >> j) & 1) ? -fw[13 - j] : fw[13 - j];
            acc = fmaf(p, g, acc);
        }
    }

#pragma unroll
    for (int off = 32; off > 0; off >>= 1) acc += __shfl_down(acc, off, 64);
    if ((t & 63) == 0) wsum[t >> 6] = acc;
    __syncthreads();
    if (t == 0) {
        float s = 0.f;
#pragma unroll
        for (int wv = 0; wv < TPB / 64; ++wv) s += wsum[wv];
        out[b] = s + fcb[0];
    }
}

extern "C" void kernel_launch(void* const* d_in, const int* in_sizes, int n_in,
                              void* d_out, int out_size, void* d_ws, size_t ws_size,
                              hipStream_t stream)
{
    const float* x   = (const float*)d_in[0];   // (512, 14)
    const float* wts = (const float*)d_in[1];   // (6, 14, 3)
    const float* fcw = (const float*)d_in[2];   // (1, 14)
    const float* fcb = (const float*)d_in[3];   // (1,)
    float* out = (float*)d_out;                 // (512,)

    const int batch = in_sizes[0] / NQ;         // 512

    qc_kernel<<<batch, TPB, 0, stream>>>(x, wts, fcw, fcb, out);
}

// Round 10
// 287.018 us; speedup vs baseline: 1.3154x; 1.3154x over previous
//
#include <hip/hip_runtime.h>

#define NQ 14
#define NL 6
#define DIM (1 << NQ)   // 16384 amplitudes
#define TPB 256

// ---------------------------------------------------------------------------
// One block (256 thr = 4 waves) per sample; state in 128 KiB static LDS
// (XOR-swizzled), 64 amps/thread as 4 sequential r[16] chunks.
//
// Allocator law (rounds 1-9): VGPR budget = 2048/(2 x waves/WG) -- it always
// assumes 2 WGs/CU; attributes don't override. TPB=256 => 256-VGPR budget;
// r[16]-chunk passes keep live ~50v => structurally spill-free (round 1 = the
// only spill-free round, was TPB=256).
//
// LAZY PERMUTATION: CNOT entangler layers are never physically applied.
// Storage map: s[h] = psi[B_l h]; CNOT layer Pi_l updates B <- Pi_l^{-1} B
// (free). Layer-l Rot on wire w pairs amps differing by physical mask
// d = C_l e_{13-w}, C_l = Pi_0...Pi_{l-1} (all compile-time). Each pass RMWs
// 16-amp cosets of span{4 masks}: addr = base(n) ^ delta(k), masks/deltas
// are constexpr literals (swizzle is XOR-linear so it folds in).
// Final expectation applies B_6 = C_6^{-1} via compile-time parity masks.
// Layer 0 (RX folded into Rot) is a product state written directly.
// ---------------------------------------------------------------------------

struct PassData {
    int smaskT[8];   // swizzled masks for t bits 0..7 (free positions)
    int smaskC[2];   // swizzled masks for the 2 chunk bits
    int delta[16];   // swizzled coset offsets
    int wires[4];    // wire index per gate j (U lookup)
    int ngates;      // 4, or 2 for the last pass (padded with free dirs)
};
struct AllData {
    PassData ps[NL][4];  // [layer][pass], layers 1..5 used
    int rmask[NQ];       // rows of B_6: logical bit q = parity(rmask[q] & h)
};

constexpr int swzc(int h) { return h ^ ((h >> 6) & 63); }

constexpr int topbit(int v) {
    int pb = 0;
    for (int z = NQ - 1; z >= 0; --z) if ((v >> z) & 1) { pb = z; break; }
    return pb;
}

constexpr AllData buildAll() {
    AllData A{};
    // Pi_l columns (construction verified exact in rounds 2-9)
    int Pi[NL][NQ] = {};
    for (int l = 0; l < NL; ++l) {
        const int rng = l + 1;
        int col[NQ] = {};
        for (int p = 0; p < NQ; ++p) col[p] = 1 << p;
        for (int w = 0; w < NQ; ++w) {
            int c = NQ - 1 - w, g = NQ - 1 - ((w + rng) % NQ);
            col[c] ^= col[g];
        }
        for (int p = 0; p < NQ; ++p) Pi[l][p] = col[p];
    }
    // C_l = Pi_0 * ... * Pi_{l-1} (columns); C_0 = I
    int C[NL + 1][NQ] = {};
    for (int p = 0; p < NQ; ++p) C[0][p] = 1 << p;
    for (int l = 0; l < NL; ++l)
        for (int p = 0; p < NQ; ++p) {
            int y = Pi[l][p], v = 0;
            for (int q = 0; q < NQ; ++q) if ((y >> q) & 1) v ^= C[l][q];
            C[l + 1][p] = v;
        }
    // passes: layer l (1..5), pass s covers logical bits p = 4s..4s+3
    for (int l = 1; l < NL; ++l)
        for (int s = 0; s < 4; ++s) {
            PassData& P = A.ps[l][s];
            const int ng = (s == 3) ? 2 : 4;
            P.ngates = ng;
            int d[4] = {};
            for (int j = 0; j < 4; ++j) P.wires[j] = 0;
            for (int j = 0; j < ng; ++j) {
                const int p = 4 * s + j;
                d[j] = C[l][p];
                P.wires[j] = 13 - p;
            }
            int nd = ng;
            // pad to 4 independent masks with unit vectors
            for (int i = 0; i < NQ && nd < 4; ++i) {
                int eb[4] = {}; int ne = 0;
                for (int a = 0; a < nd; ++a) {
                    int v = d[a];
                    for (int b = 0; b < ne; ++b)
                        if ((v >> topbit(eb[b])) & 1) v ^= eb[b];
                    if (v) eb[ne++] = v;
                }
                int vv = 1 << i;
                for (int b = 0; b < ne; ++b)
                    if ((vv >> topbit(eb[b])) & 1) vv ^= eb[b];
                if (vv) d[nd++] = 1 << i;
            }
            // pivot positions of span{d}; free = complement (10 bits)
            int eb[4] = {}; int ne = 0; int piv = 0;
            for (int a = 0; a < 4; ++a) {
                int v = d[a];
                for (int b = 0; b < ne; ++b)
                    if ((v >> topbit(eb[b])) & 1) v ^= eb[b];
                eb[ne++] = v;
                piv |= 1 << topbit(v);
            }
            int nf = 0;
            for (int i = 0; i < NQ; ++i) {
                if ((piv >> i) & 1) continue;
                if (nf < 8) P.smaskT[nf] = swzc(1 << i);
                else        P.smaskC[nf - 8] = swzc(1 << i);
                ++nf;
            }
            for (int k = 0; k < 16; ++k) {
                int v = 0;
                for (int j = 0; j < 4; ++j) if ((k >> j) & 1) v ^= d[j];
                P.delta[k] = swzc(v);
            }
        }
    // rmask = rows of C_6^{-1} (Gauss-Jordan on row representation)
    {
        unsigned int M[NQ] = {}, Inv[NQ] = {};
        for (int q = 0; q < NQ; ++q) {
            M[q] = 0;
            for (int p = 0; p < NQ; ++p) M[q] |= (unsigned)((C[NL][p] >> q) & 1) << p;
            Inv[q] = 1u << q;
        }
        for (int cp = 0; cp < NQ; ++cp) {
            int pv = cp;
            while (!((M[pv] >> cp) & 1)) ++pv;
            unsigned tmp = M[pv]; M[pv] = M[cp]; M[cp] = tmp;
            tmp = Inv[pv]; Inv[pv] = Inv[cp]; Inv[cp] = tmp;
            for (int q = 0; q < NQ; ++q)
                if (q != cp && ((M[q] >> cp) & 1)) { M[q] ^= M[cp]; Inv[q] ^= Inv[cp]; }
        }
        for (int q = 0; q < NQ; ++q) A.rmask[q] = (int)Inv[q];
    }
    return A;
}

constexpr AllData AD = buildAll();

__device__ __forceinline__ float2 cmul(float2 a, float2 b) {
    return make_float2(a.x * b.x - a.y * b.y, a.x * b.y + a.y * b.x);
}

__device__ __forceinline__ void gate2(float2 u0, float2 u1, float2 u2, float2 u3,
                                      float2& A, float2& C) {
    float2 a = A, c = C, na, nc;
    na.x = u0.x * a.x - u0.y * a.y + u1.x * c.x - u1.y * c.y;
    na.y = u0.x * a.y + u0.y * a.x + u1.x * c.y + u1.y * c.x;
    nc.x = u2.x * a.x - u2.y * a.y + u3.x * c.x - u3.y * c.y;
    nc.y = u2.x * a.y + u2.y * a.x + u3.x * c.y + u3.y * c.x;
    A = na; C = nc;
}

template <int L, int S>
__device__ __forceinline__ void doPass(float2* st, const float2 (*U)[4], int t) {
    constexpr PassData P = AD.ps[L][S];
    int base = 0;
#pragma unroll
    for (int i = 0; i < 8; ++i) base ^= (-((t >> i) & 1)) & P.smaskT[i];
#pragma unroll
    for (int ch = 0; ch < 4; ++ch) {
        const int cbase = base ^ ((ch & 1) ? P.smaskC[0] : 0)
                               ^ ((ch & 2) ? P.smaskC[1] : 0);
        float2 r[16];
#pragma unroll
        for (int k = 0; k < 16; ++k) r[k] = st[cbase ^ P.delta[k]];
#pragma unroll
        for (int j = 0; j < 4; ++j) {
            if (j < P.ngates) {   // P constexpr -> folds after unroll
                const float2* u = U[L * NQ + P.wires[j]];
                const float2 u0 = u[0], u1 = u[1], u2 = u[2], u3 = u[3];
#pragma unroll
                for (int p8 = 0; p8 < 8; ++p8) {
                    const int k0 = ((p8 >> j) << (j + 1)) | (p8 & ((1 << j) - 1));
                    gate2(u0, u1, u2, u3, r[k0], r[k0 | (1 << j)]);
                }
            }
        }
#pragma unroll
        for (int k = 0; k < 16; ++k) st[cbase ^ P.delta[k]] = r[k];
    }
}

__global__ __launch_bounds__(TPB)
void qc_kernel(const float* __restrict__ x,
               const float* __restrict__ wts,
               const float* __restrict__ fcw,
               const float* __restrict__ fcb,
               float* __restrict__ out)
{
    __shared__ float2 st[DIM];               // 128 KiB, slot = swz(h)
    __shared__ float2 U[NL * NQ][4];
    __shared__ float2 R[NQ][4];
    __shared__ float wsum[TPB / 64];

    const int b = blockIdx.x;
    const int t = threadIdx.x;

    // gate matrices
    if (t < NQ) {
        float th = 0.5f * x[b * NQ + t];
        float c = cosf(th), s = sinf(th);
        R[t][0] = make_float2(c, 0.f);
        R[t][1] = make_float2(0.f, -s);
        R[t][2] = make_float2(0.f, -s);
        R[t][3] = make_float2(c, 0.f);
    }
    if (t >= 64 && t < 64 + NL * NQ) {
        int g = t - 64;
        float phi = wts[g * 3 + 0];
        float th  = wts[g * 3 + 1];
        float om  = wts[g * 3 + 2];
        float c = cosf(0.5f * th), s = sinf(0.5f * th);
        float aa = 0.5f * (phi + om), dd = 0.5f * (phi - om);
        float ca = cosf(aa), sa = sinf(aa);
        float cd = cosf(dd), sd = sinf(dd);
        U[g][0] = make_float2( ca * c, -sa * c);
        U[g][1] = make_float2(-cd * s, -sd * s);
        U[g][2] = make_float2( cd * s, -sd * s);
        U[g][3] = make_float2( ca * c,  sa * c);
    }
    __syncthreads();

    // fold RX into layer-0 Rot: U0 = Rot * RX
    if (t < NQ) {
        float2 a00 = U[t][0], a01 = U[t][1], a10 = U[t][2], a11 = U[t][3];
        float2 b00 = R[t][0], b01 = R[t][1], b10 = R[t][2], b11 = R[t][3];
        auto ca2 = [](float2 p, float2 q) { return make_float2(p.x + q.x, p.y + q.y); };
        U[t][0] = ca2(cmul(a00, b00), cmul(a01, b10));
        U[t][1] = ca2(cmul(a00, b01), cmul(a01, b11));
        U[t][2] = ca2(cmul(a10, b00), cmul(a11, b10));
        U[t][3] = ca2(cmul(a10, b01), cmul(a11, b11));
    }
    __syncthreads();

    // ---- layer 0: product state, identity storage map ----
    // h = (t<<6) | m; slot = (t<<6) ^ (t&63) ^ m. h bit p <-> wire 13-p.
    {
        float2 A2 = make_float2(1.f, 0.f);
#pragma unroll
        for (int i = 0; i < 8; ++i)          // h bit 6+i = t bit i -> wire 7-i
            A2 = cmul(A2, ((t >> i) & 1) ? U[7 - i][2] : U[7 - i][0]);
        float2 t01[4], t23[4], t45[4];
#pragma unroll
        for (int a = 0; a < 4; ++a) {
            t01[a] = cmul((a & 1) ? U[13][2] : U[13][0], (a & 2) ? U[12][2] : U[12][0]);
            t23[a] = cmul((a & 1) ? U[11][2] : U[11][0], (a & 2) ? U[10][2] : U[10][0]);
            t45[a] = cmul((a & 1) ? U[9][2]  : U[9][0],  (a & 2) ? U[8][2]  : U[8][0]);
        }
        const int abase = (t << 6) ^ (t & 63);
#pragma unroll
        for (int m = 0; m < 64; ++m)
            st[abase ^ m] = cmul(cmul(A2, t45[m >> 4]),
                                 cmul(t01[m & 3], t23[(m >> 2) & 3]));
    }
    __syncthreads();

    // ---- layers 1..5: 4 RMW passes each; no physical permutation ever ----
    doPass<1, 0>(st, U, t); __syncthreads();
    doPass<1, 1>(st, U, t); __syncthreads();
    doPass<1, 2>(st, U, t); __syncthreads();
    doPass<1, 3>(st, U, t); __syncthreads();
    doPass<2, 0>(st, U, t); __syncthreads();
    doPass<2, 1>(st, U, t); __syncthreads();
    doPass<2, 2>(st, U, t); __syncthreads();
    doPass<2, 3>(st, U, t); __syncthreads();
    doPass<3, 0>(st, U, t); __syncthreads();
    doPass<3, 1>(st, U, t); __syncthreads();
    doPass<3, 2>(st, U, t); __syncthreads();
    doPass<3, 3>(st, U, t); __syncthreads();
    doPass<4, 0>(st, U, t); __syncthreads();
    doPass<4, 1>(st, U, t); __syncthreads();
    doPass<4, 2>(st, U, t); __syncthreads();
    doPass<4, 3>(st, U, t); __syncthreads();
    doPass<5, 0>(st, U, t); __syncthreads();
    doPass<5, 1>(st, U, t); __syncthreads();
    doPass<5, 2>(st, U, t); __syncthreads();
    doPass<5, 3>(st, U, t); __syncthreads();

    // ---- fused expectation + FC via B_6 parity masks ----
    float fw[NQ];
#pragma unroll
    for (int w = 0; w < NQ; ++w) fw[w] = fcw[w];
    float fv[NQ];
#pragma unroll
    for (int w = 0; w < NQ; ++w) {
        const int par = __popc(AD.rmask[13 - w] & (t << 6)) & 1;
        fv[w] = par ? -fw[w] : fw[w];
    }
    const int abase = (t << 6) ^ (t & 63);
    float acc = 0.f;
#pragma unroll
    for (int m = 0; m < 64; ++m) {
        const float2 a = st[abase ^ m];
        const float p = a.x * a.x + a.y * a.y;
        float g = 0.f;
#pragma unroll
        for (int w = 0; w < NQ; ++w)
            g += ((__popc(AD.rmask[13 - w] & m) & 1) ? -fv[w] : fv[w]);  // folds
        acc = fmaf(p, g, acc);
    }

#pragma unroll
    for (int off = 32; off > 0; off >>= 1) acc += __shfl_down(acc, off, 64);
    if ((t & 63) == 0) wsum[t >> 6] = acc;
    __syncthreads();
    if (t == 0) {
        float s = 0.f;
#pragma unroll
        for (int wv = 0; wv < TPB / 64; ++wv) s += wsum[wv];
        out[b] = s + fcb[0];
    }
}

extern "C" void kernel_launch(void* const* d_in, const int* in_sizes, int n_in,
                              void* d_out, int out_size, void* d_ws, size_t ws_size,
                              hipStream_t stream)
{
    const float* x   = (const float*)d_in[0];   // (512, 14)
    const float* wts = (const float*)d_in[1];   // (6, 14, 3)
    const float* fcw = (const float*)d_in[2];   // (1, 14)
    const float* fcb = (const float*)d_in[3];   // (1,)
    float* out = (float*)d_out;                 // (512,)

    const int batch = in_sizes[0] / NQ;         // 512

    qc_kernel<<<batch, TPB, 0, stream>>>(x, wts, fcw, fcb, out);
}

// Round 12
// 203.006 us; speedup vs baseline: 1.8598x; 1.4138x over previous
//
#include <hip/hip_runtime.h>

#define NQ 14
#define NL 6
#define DIM (1 << NQ)   // 16384 amplitudes
#define TPB 256

// ---------------------------------------------------------------------------
// One block (256 thr = 4 waves) per sample; state in 128 KiB static LDS
// (XOR-swizzled), 64 amps/thread as 2 sequential r[32] chunks.
// TPB=256 is load-bearing: allocator law (rounds 1-10): VGPR budget =
// 2048/(2 x waves/WG); 256 thr => 256-VGPR budget => r[32] passes fit
// spill-free (round 10: FETCH dropped 287MB -> 2MB at this config).
//
// LAZY PERMUTATION (verified round 10): CNOT entangler layers are never
// physically applied. Layer-l Rot on wire w pairs amps differing by physical
// mask d = C_l e_{13-w} (C_l = Pi_0..Pi_{l-1}, compile-time). 3 passes/layer
// (5+5+4 gate bits), RMW on 32-amp cosets; final expectation applies
// C_6^{-1} via compile-time parity masks. Layer 0 = product state.
//
// NEW this round:
//  * v_pk_fma_f32 packed-f32 gate kernel (SU(2) form): 8 VOP3P instrs per
//    amp-pair per gate vs 16 scalar -- halves the dominant VALU stream.
//    Full f32 precision (packed ops are 2x independent f32 lanes).
//  * Bank-aware lane masks: lane bits t0..t3 get free directions whose
//    swizzled projections onto addr mod 16 (bank-pair index) are
//    GF(2)-independent -> 4 lanes/bank-pair = conflict-free b64 floor.
// ---------------------------------------------------------------------------

using cplx = __attribute__((ext_vector_type(2))) float;

struct PassData {
    int smaskL[6];   // swizzled masks for lane bits t0..t5
    int smaskW[2];   // swizzled masks for wave bits t6,t7
    int smaskC;      // swizzled mask for the chunk bit
    int delta[32];   // swizzled coset offsets
    int wires[5];    // wire index per gate j
    int ngates;      // 5, or 4 for the last pass (padded with a free dir)
};
struct AllData {
    PassData ps[NL][3];  // [layer][pass], layers 1..5 used
    int rmask[NQ];       // rows of C_6^{-1}: logical bit q = parity(rmask[q]&h)
};

constexpr int swzc(int h) { return h ^ ((h >> 6) & 63); }

constexpr int topbit(int v) {
    int pb = 0;
    for (int z = NQ - 1; z >= 0; --z) if ((v >> z) & 1) { pb = z; break; }
    return pb;
}

constexpr AllData buildAll() {
    AllData A{};
    // Pi_l columns (construction verified exact rounds 2-10)
    int Pi[NL][NQ] = {};
    for (int l = 0; l < NL; ++l) {
        const int rng = l + 1;
        int col[NQ] = {};
        for (int p = 0; p < NQ; ++p) col[p] = 1 << p;
        for (int w = 0; w < NQ; ++w) {
            int c = NQ - 1 - w, g = NQ - 1 - ((w + rng) % NQ);
            col[c] ^= col[g];
        }
        for (int p = 0; p < NQ; ++p) Pi[l][p] = col[p];
    }
    // C_l = Pi_0 * ... * Pi_{l-1} (columns); C_0 = I
    int C[NL + 1][NQ] = {};
    for (int p = 0; p < NQ; ++p) C[0][p] = 1 << p;
    for (int l = 0; l < NL; ++l)
        for (int p = 0; p < NQ; ++p) {
            int y = Pi[l][p], v = 0;
            for (int q = 0; q < NQ; ++q) if ((y >> q) & 1) v ^= C[l][q];
            C[l + 1][p] = v;
        }
    // passes: layer l (1..5), pass s: s0 -> p 0..4, s1 -> p 5..9, s2 -> p 10..13
    for (int l = 1; l < NL; ++l)
        for (int s = 0; s < 3; ++s) {
            PassData& P = A.ps[l][s];
            const int ng = (s == 2) ? 4 : 5;
            P.ngates = ng;
            int d[5] = {};
            for (int j = 0; j < 5; ++j) P.wires[j] = 0;
            for (int j = 0; j < ng; ++j) {
                const int p = (s == 2) ? (10 + j) : (s * 5 + j);
                d[j] = C[l][p];
                P.wires[j] = 13 - p;
            }
            // pad to 5 independent masks with unit vectors
            int nd = ng;
            for (int i = 0; i < NQ && nd < 5; ++i) {
                int eb[5] = {}; int ne = 0;
                for (int a2 = 0; a2 < nd; ++a2) {
                    int v = d[a2];
                    for (int b2 = 0; b2 < ne; ++b2)
                        if ((v >> topbit(eb[b2])) & 1) v ^= eb[b2];
                    if (v) eb[ne++] = v;
                }
                int vv = 1 << i;
                for (int b2 = 0; b2 < ne; ++b2)
                    if ((vv >> topbit(eb[b2])) & 1) vv ^= eb[b2];
                if (vv) d[nd++] = 1 << i;
            }
            // pivot positions of span{d}; free positions = complement (9)
            int eb[5] = {}; int ne = 0; int piv = 0;
            for (int a2 = 0; a2 < 5; ++a2) {
                int v = d[a2];
                for (int b2 = 0; b2 < ne; ++b2)
                    if ((v >> topbit(eb[b2])) & 1) v ^= eb[b2];
                eb[ne++] = v;
                piv |= 1 << topbit(v);
            }
            int fm[9] = {}; int nfm = 0;
            for (int i = 0; i < NQ; ++i)
                if (!((piv >> i) & 1)) fm[nfm++] = swzc(1 << i);
            // greedy: free dirs with independent projections on addr mod 16
            // (bank-pair index) go to lane bits first -> conflict-free b64
            int order[9] = {}; bool used[9] = {};
            int no = 0;
            int pb[4] = {}; int npb = 0;
            for (int i = 0; i < 9 && npb < 4; ++i) {
                int v = fm[i] & 15;
                for (int b2 = 0; b2 < npb; ++b2)
                    if ((v >> topbit(pb[b2])) & 1) v ^= pb[b2];
                if (v) { pb[npb++] = v; order[no++] = i; used[i] = true; }
            }
            for (int i = 0; i < 9; ++i) if (!used[i]) order[no++] = i;
            for (int i = 0; i < 6; ++i) P.smaskL[i] = fm[order[i]];
            P.smaskW[0] = fm[order[6]];
            P.smaskW[1] = fm[order[7]];
            P.smaskC    = fm[order[8]];
            for (int k = 0; k < 32; ++k) {
                int v = 0;
                for (int j = 0; j < 5; ++j) if ((k >> j) & 1) v ^= d[j];
                P.delta[k] = swzc(v);
            }
        }
    // rmask = rows of C_6^{-1}
    {
        unsigned int M[NQ] = {}, Inv[NQ] = {};
        for (int q = 0; q < NQ; ++q) {
            M[q] = 0;
            for (int p = 0; p < NQ; ++p) M[q] |= (unsigned)((C[NL][p] >> q) & 1) << p;
            Inv[q] = 1u << q;
        }
        for (int cp = 0; cp < NQ; ++cp) {
            int pv = cp;
            while (!((M[pv] >> cp) & 1)) ++pv;
            unsigned tmp = M[pv]; M[pv] = M[cp]; M[cp] = tmp;
            tmp = Inv[pv]; Inv[pv] = Inv[cp]; Inv[cp] = tmp;
            for (int q = 0; q < NQ; ++q)
                if (q != cp && ((M[q] >> cp) & 1)) { M[q] ^= M[cp]; Inv[q] ^= Inv[cp]; }
        }
        for (int q = 0; q < NQ; ++q) A.rmask[q] = (int)Inv[q];
    }
    return A;
}

constexpr AllData AD = buildAll();

// d = a * b (complex), packed f32: 2 VOP3P instrs
__device__ __forceinline__ cplx cmulpk(cplx a, cplx b) {
    cplx d;
    asm("v_pk_mul_f32 %0, %1, %2 op_sel:[0,0] op_sel_hi:[0,1]\n\t"
        "v_pk_fma_f32 %0, %1, %2, %0 op_sel:[1,1,0] op_sel_hi:[1,0,1] neg_lo:[1,0,0]\n\t"
        : "=&v"(d) : "v"(a), "v"(b));
    return d;
}

// SU(2) gate on amp pair (A,C):
//   A' = u0*A + u1*C ; C' = -conj(u1)*A + conj(u0)*C      (8 VOP3P instrs)
__device__ __forceinline__ void gate2pk(cplx u0, cplx u1, cplx& A, cplx& C) {
    cplx na, nc;
    asm(// na = (u0x*ax, u0x*ay) ; nc = (-u1x*ax, -u1x*ay)
        "v_pk_mul_f32 %0, %2, %4 op_sel:[0,0] op_sel_hi:[0,1]\n\t"
        "v_pk_mul_f32 %1, %3, %4 op_sel:[0,0] op_sel_hi:[0,1] neg_lo:[1,0] neg_hi:[1,0]\n\t"
        // na += (-u0y*ay, u0y*ax) ; nc += (-u1y*ay, u1y*ax)
        "v_pk_fma_f32 %0, %2, %4, %0 op_sel:[1,1,0] op_sel_hi:[1,0,1] neg_lo:[1,0,0]\n\t"
        "v_pk_fma_f32 %1, %3, %4, %1 op_sel:[1,1,0] op_sel_hi:[1,0,1] neg_lo:[1,0,0]\n\t"
        // na += (u1x*cx, u1x*cy) ; nc += (u0x*cx, u0x*cy)
        "v_pk_fma_f32 %0, %3, %5, %0 op_sel:[0,0,0] op_sel_hi:[0,1,1]\n\t"
        "v_pk_fma_f32 %1, %2, %5, %1 op_sel:[0,0,0] op_sel_hi:[0,1,1]\n\t"
        // na += (-u1y*cy, u1y*cx) ; nc += (u0y*cy, -u0y*cx)
        "v_pk_fma_f32 %0, %3, %5, %0 op_sel:[1,1,0] op_sel_hi:[1,0,1] neg_lo:[1,0,0]\n\t"
        "v_pk_fma_f32 %1, %2, %5, %1 op_sel:[1,1,0] op_sel_hi:[1,0,1] neg_hi:[1,0,0]\n\t"
        : "=&v"(na), "=&v"(nc)
        : "v"(u0), "v"(u1), "v"(A), "v"(C));
    A = na; C = nc;
}

template <int L, int S>
__device__ __forceinline__ void doPass(cplx* st, const cplx (*U)[4], int t) {
    constexpr PassData P = AD.ps[L][S];
    int base = 0;
#pragma unroll
    for (int i = 0; i < 6; ++i) base ^= (-((t >> i) & 1)) & P.smaskL[i];
#pragma unroll
    for (int i = 0; i < 2; ++i) base ^= (-((t >> (6 + i)) & 1)) & P.smaskW[i];
    cplx g0[5], g1[5];
#pragma unroll
    for (int j = 0; j < 5; ++j)
        if (j < P.ngates) {
            g0[j] = U[L * NQ + P.wires[j]][0];
            g1[j] = U[L * NQ + P.wires[j]][1];
        }
#pragma unroll
    for (int ch = 0; ch < 2; ++ch) {
        const int cbase = base ^ (ch ? P.smaskC : 0);
        cplx r[32];
#pragma unroll
        for (int k = 0; k < 32; ++k) r[k] = st[cbase ^ P.delta[k]];
#pragma unroll
        for (int j = 0; j < 5; ++j) {
            if (j < P.ngates) {
#pragma unroll
                for (int p = 0; p < 16; ++p) {
                    const int k0 = ((p >> j) << (j + 1)) | (p & ((1 << j) - 1));
                    gate2pk(g0[j], g1[j], r[k0], r[k0 | (1 << j)]);
                }
            }
        }
#pragma unroll
        for (int k = 0; k < 32; ++k) st[cbase ^ P.delta[k]] = r[k];
    }
}

__global__ __launch_bounds__(TPB)
void qc_kernel(const float* __restrict__ x,
               const float* __restrict__ wts,
               const float* __restrict__ fcw,
               const float* __restrict__ fcb,
               float* __restrict__ out)
{
    __shared__ cplx st[DIM];                 // 128 KiB, slot = swz(h)
    __shared__ cplx U[NL * NQ][4];
    __shared__ cplx R[NQ][4];
    __shared__ float wsum[TPB / 64];

    const int b = blockIdx.x;
    const int t = threadIdx.x;

    // gate matrices
    if (t < NQ) {
        float th = 0.5f * x[b * NQ + t];
        float c = cosf(th), s = sinf(th);
        R[t][0] = cplx{c, 0.f};
        R[t][1] = cplx{0.f, -s};
        R[t][2] = cplx{0.f, -s};
        R[t][3] = cplx{c, 0.f};
    }
    if (t >= 64 && t < 64 + NL * NQ) {
        int g = t - 64;
        float phi = wts[g * 3 + 0];
        float th  = wts[g * 3 + 1];
        float om  = wts[g * 3 + 2];
        float c = cosf(0.5f * th), s = sinf(0.5f * th);
        float aa = 0.5f * (phi + om), dd = 0.5f * (phi - om);
        float ca = cosf(aa), sa = sinf(aa);
        float cd = cosf(dd), sd = sinf(dd);
        U[g][0] = cplx{ ca * c, -sa * c};
        U[g][1] = cplx{-cd * s, -sd * s};
        U[g][2] = cplx{ cd * s, -sd * s};
        U[g][3] = cplx{ ca * c,  sa * c};
    }
    __syncthreads();

    // fold RX into layer-0 Rot: U0 = Rot * RX (scalar, runs once, 14 threads)
    if (t < NQ) {
        cplx a00 = U[t][0], a01 = U[t][1], a10 = U[t][2], a11 = U[t][3];
        cplx b00 = R[t][0], b01 = R[t][1], b10 = R[t][2], b11 = R[t][3];
        auto cm = [](cplx p, cplx q) {
            return cplx{p.x * q.x - p.y * q.y, p.x * q.y + p.y * q.x};
        };
        U[t][0] = cm(a00, b00) + cm(a01, b10);
        U[t][1] = cm(a00, b01) + cm(a01, b11);
        U[t][2] = cm(a10, b00) + cm(a11, b10);
        U[t][3] = cm(a10, b01) + cm(a11, b11);
    }
    __syncthreads();

    // ---- layer 0: product state, identity storage map ----
    // h = (t<<6)|m; slot = (t<<6)^(t&63)^m. h bit p <-> wire 13-p.
    {
        cplx A2 = cplx{1.f, 0.f};
#pragma unroll
        for (int i = 0; i < 8; ++i)          // h bit 6+i = t bit i -> wire 7-i
            A2 = cmulpk(A2, ((t >> i) & 1) ? U[7 - i][2] : U[7 - i][0]);
        cplx t01[4], t23[4], t45[4];
#pragma unroll
        for (int a = 0; a < 4; ++a) {
            t01[a] = cmulpk((a & 1) ? U[13][2] : U[13][0], (a & 2) ? U[12][2] : U[12][0]);
            t23[a] = cmulpk((a & 1) ? U[11][2] : U[11][0], (a & 2) ? U[10][2] : U[10][0]);
            t45[a] = cmulpk((a & 1) ? U[9][2]  : U[9][0],  (a & 2) ? U[8][2]  : U[8][0]);
        }
        const int abase = (t << 6) ^ (t & 63);
#pragma unroll
        for (int m = 0; m < 64; ++m)
            st[abase ^ m] = cmulpk(cmulpk(A2, t45[m >> 4]),
                                   cmulpk(t01[m & 3], t23[(m >> 2) & 3]));
    }
    __syncthreads();

    // ---- layers 1..5: 3 RMW passes each (5+5+4 gates) ----
    doPass<1, 0>(st, U, t); __syncthreads();
    doPass<1, 1>(st, U, t); __syncthreads();
    doPass<1, 2>(st, U, t); __syncthreads();
    doPass<2, 0>(st, U, t); __syncthreads();
    doPass<2, 1>(st, U, t); __syncthreads();
    doPass<2, 2>(st, U, t); __syncthreads();
    doPass<3, 0>(st, U, t); __syncthreads();
    doPass<3, 1>(st, U, t); __syncthreads();
    doPass<3, 2>(st, U, t); __syncthreads();
    doPass<4, 0>(st, U, t); __syncthreads();
    doPass<4, 1>(st, U, t); __syncthreads();
    doPass<4, 2>(st, U, t); __syncthreads();
    doPass<5, 0>(st, U, t); __syncthreads();
    doPass<5, 1>(st, U, t); __syncthreads();
    doPass<5, 2>(st, U, t); __syncthreads();

    // ---- fused expectation + FC via C_6^{-1} parity masks ----
    float fw[NQ];
#pragma unroll
    for (int w = 0; w < NQ; ++w) fw[w] = fcw[w];
    float fv[NQ];
#pragma unroll
    for (int w = 0; w < NQ; ++w) {
        const int par = __popc(AD.rmask[13 - w] & (t << 6)) & 1;
        fv[w] = par ? -fw[w] : fw[w];
    }
    const int abase = (t << 6) ^ (t & 63);
    float acc = 0.f;
#pragma unroll
    for (int m = 0; m < 64; ++m) {
        const cplx a = st[abase ^ m];
        const float p = a.x * a.x + a.y * a.y;
        float g = 0.f;
#pragma unroll
        for (int w = 0; w < NQ; ++w)
            g += ((__popc(AD.rmask[13 - w] & m) & 1) ? -fv[w] : fv[w]);  // folds
        acc = fmaf(p, g, acc);
    }

#pragma unroll
    for (int off = 32; off > 0; off >>= 1) acc += __shfl_down(acc, off, 64);
    if ((t & 63) == 0) wsum[t >> 6] = acc;
    __syncthreads();
    if (t == 0) {
        float s = 0.f;
#pragma unroll
        for (int wv = 0; wv < TPB / 64; ++wv) s += wsum[wv];
        out[b] = s + fcb[0];
    }
}

extern "C" void kernel_launch(void* const* d_in, const int* in_sizes, int n_in,
                              void* d_out, int out_size, void* d_ws, size_t ws_size,
                              hipStream_t stream)
{
    const float* x   = (const float*)d_in[0];   // (512, 14)
    const float* wts = (const float*)d_in[1];   // (6, 14, 3)
    const float* fcw = (const float*)d_in[2];   // (1, 14)
    const float* fcb = (const float*)d_in[3];   // (1,)
    float* out = (float*)d_out;                 // (512,)

    const int batch = in_sizes[0] / NQ;         // 512

    qc_kernel<<<batch, TPB, 0, stream>>>(x, wts, fcw, fcb, out);
}